// Round 9
// baseline (300.564 us; speedup 1.0000x reference)
//
#include <hip/hip_runtime.h>

// ---------------------------------------------------------------------------
// 2-layer GCN forward, 8-launch pipeline (r19).
// prepW -> front(hist+gemm1 fused) -> scan1 -> place -> degsort
// -> gather128 -> gemm2 -> gather40.
// r18: gather128 request-rate analysis: 12.8M 4B-per-lane dword gathers at
//      3.55 TB/s beyond-L2. r19: wave reads the full 256B row per edge via
//      16-lane uint4 groups (4x fewer requests; 16-edge block 80->44 wave
//      inst). Cross-group partials reduced with 2 shfl_xor rounds. Same
//      bytes, same f32-accum numerics.
// r19b: scan2 (1-block kernel, full-grid bubble) deleted: place/degsort
//      scan the ~598-entry bsum locally in LDS (2.4KB, trivial).
// gather40: r18 sliced variant (H2 slice-major [2][n][10]u32, 4MB/slice
//      fits per-XCD L2; slice = blockIdx&1).
// Graveyard: r15 LDS-atomic push (op-count wall), r16 glds+shfl (shuffle
// cost > dest-VGPR serialization), r17 global-atomic deg hist (4-line
// contention = 270us), r12-r14 sliced reg-gathers (latency-bound 97-102).
// ---------------------------------------------------------------------------

typedef unsigned int u32;
typedef unsigned short u16;
typedef __attribute__((ext_vector_type(8))) short short8;
typedef __attribute__((ext_vector_type(4))) float floatx4;

#define CHUNK 4096            // edges per histogram/place block

#define REP7(M)  M(0) M(1) M(2) M(3) M(4) M(5) M(6)
#define REP8(M)  M(0) M(1) M(2) M(3) M(4) M(5) M(6) M(7)

static __device__ inline u16 f2bf(float f) {
    u32 u = __float_as_uint(f);
    return (u16)((u + 0x7FFFu + ((u >> 16) & 1u)) >> 16);   // RNE
}
static __device__ inline u32 pack2(float a, float b) {
    return (u32)f2bf(a) | ((u32)f2bf(b) << 16);
}
static __device__ inline float bflo(u32 u) { return __uint_as_float(u << 16); }
static __device__ inline float bfhi(u32 u) { return __uint_as_float(u & 0xffff0000u); }

// wave-local int64-vs-int32 storage detection: sample 64 odd int32 slots of
// the first 64 index values; all-zero => int64 (high words), else int32.
static __device__ inline bool detect_is64(const int* e32, int lane) {
    bool nz = e32[2 * lane + 1] != 0;
    return __ballot(nz) == 0ull;
}

// ---- W1 [128,128] -> WTb [c][k] bf16; W2 [128,40] -> W2Tb [48][128] bf16 ---
__global__ void k_prepW(const float* __restrict__ W1, const float* __restrict__ W2,
                        u16* __restrict__ WTb, u16* __restrict__ W2Tb) {
    int id = blockIdx.x * 256 + threadIdx.x;
    if (id < 16384) {
        int k = id >> 7, c = id & 127;           // W1[k][c]
        WTb[c * 128 + k] = f2bf(W1[id]);
    } else {
        int id2 = id - 16384;
        if (id2 < 6144) {                        // 48 x 128, zero-pad cols 40+
            int c = id2 >> 7, k = id2 & 127;
            W2Tb[id2] = f2bf(c < 40 ? W2[k * 40 + c] : 0.f);
        }
    }
}

// ---- fused front: blocks [0,NC) = per-chunk bucket histogram,
//      blocks [NC, NC+G1) = GEMM1 (MFMA, unscaled bf16 out) -----------------
__global__ __launch_bounds__(256) void k_front(const void* __restrict__ e_raw,
                                               int E, int NC, int NB,
                                               int* __restrict__ histG,
                                               const float* __restrict__ X,
                                               const u16* __restrict__ WTb,
                                               u16* __restrict__ H1s, int n) {
    __shared__ u32 smem[64 * 68 + 128 * 68];     // 52,224 B, shared by roles
    const int tid = threadIdx.x;
    if ((int)blockIdx.x < NC) {
        // ---------- histogram role ----------
        int* h = (int*)smem;
        h[tid] = 0; h[tid + 256] = 0;
        __syncthreads();
        const int* e32 = (const int*)e_raw;
        bool is64 = detect_is64(e32, tid & 63);
        int c = blockIdx.x;
        int j0 = c * CHUNK, j1 = min(E, j0 + CHUNK);
        for (int j = j0 + tid; j < j1; j += 256) {
            int d = is64 ? (int)((const long long*)e_raw)[E + j] : e32[E + j];
            atomicAdd(&h[d >> 8], 1);
        }
        __syncthreads();
        for (int b = tid; b < NB; b += 256) histG[(size_t)b * NC + c] = h[b];
        return;
    }
    // ---------- GEMM1 role ----------
    u32* As = smem;                  // [row][k/2], stride 68
    u32* Bs = smem + 64 * 68;        // [col][k/2], stride 68
    const int row0 = ((int)blockIdx.x - NC) * 64;
#pragma unroll
    for (int it = 0; it < 8; it++) {        // stage X, f32 -> bf16
        int i = tid + it * 256;             // 2048 float4
        int r = i >> 5;
        int c4 = (i & 31) << 2;
        int gr = row0 + r;
        float4 v = make_float4(0.f, 0.f, 0.f, 0.f);
        if (gr < n) v = *(const float4*)(X + (size_t)gr * 128 + c4);
        uint2 p;
        p.x = pack2(v.x, v.y);
        p.y = pack2(v.z, v.w);
        *(uint2*)&As[r * 68 + (c4 >> 1)] = p;
    }
#pragma unroll
    for (int it = 0; it < 8; it++) {        // stage WTb (straight copy)
        int i = tid + it * 256;             // 2048 uint4
        int r = i >> 4;
        int c4 = (i & 15) << 2;
        *(uint4*)&Bs[r * 68 + c4] =
            *(const uint4*)((const u32*)WTb + (size_t)r * 64 + c4);
    }
    __syncthreads();

    const int lane = tid & 63;
    const int wave = tid >> 6;
    const int wr = wave >> 1;
    const int wc = wave & 1;
    const int mrow = lane & 15;
    const int quad = lane >> 4;

    floatx4 acc[2][4] = {};
    for (int k0 = 0; k0 < 128; k0 += 32) {
        int koff = (k0 >> 1) + quad * 4;
        short8 a[2], b[4];
#pragma unroll
        for (int i = 0; i < 2; i++)
            a[i] = *(const short8*)&As[((wr * 2 + i) * 16 + mrow) * 68 + koff];
#pragma unroll
        for (int j = 0; j < 4; j++)
            b[j] = *(const short8*)&Bs[((wc * 4 + j) * 16 + mrow) * 68 + koff];
#pragma unroll
        for (int i = 0; i < 2; i++)
#pragma unroll
            for (int j = 0; j < 4; j++)
                acc[i][j] = __builtin_amdgcn_mfma_f32_16x16x32_bf16(
                    a[i], b[j], acc[i][j], 0, 0, 0);
    }
#pragma unroll
    for (int i = 0; i < 2; i++) {
        int gr0 = row0 + (wr * 2 + i) * 16 + quad * 4;
#pragma unroll
        for (int j = 0; j < 4; j++) {
            int gcol = (wc * 4 + j) * 16 + mrow;
#pragma unroll
            for (int rg = 0; rg < 4; rg++) {
                int grow = gr0 + rg;
                if (grow < n)
                    H1s[(size_t)grow * 128 + gcol] = f2bf(acc[i][j][rg]);
            }
        }
    }
}

// ---- exclusive scan over histG (NH entries), partial + block sums ----------
// bsum stays RAW per-block totals; consumers scan it locally (r19b).
__global__ void k_scan1(const int* __restrict__ in, int* __restrict__ out,
                        int* __restrict__ bsum, int n) {
    __shared__ int sh[256];
    int i = blockIdx.x * 256 + threadIdx.x;
    int v = (i < n) ? in[i] : 0;
    sh[threadIdx.x] = v;
    __syncthreads();
    for (int off = 1; off < 256; off <<= 1) {
        int t = (threadIdx.x >= off) ? sh[threadIdx.x - off] : 0;
        __syncthreads();
        sh[threadIdx.x] += t;
        __syncthreads();
    }
    if (i < n) out[i] = sh[threadIdx.x] - v;             // exclusive partial
    if (threadIdx.x == 255) bsum[blockIdx.x] = sh[255];
}

// local exclusive scan of bsum[0..nb) (nb<=1024) into bs[] (LDS), using
// scratch sct[256]. All threads participate; result valid after return.
static __device__ inline void scan_bsum_local(const int* __restrict__ bsum,
                                              int nb, int* bs, int* sct,
                                              int t) {
    int carry = 0;
    for (int base = 0; base < nb; base += 256) {
        int v = (base + t < nb) ? bsum[base + t] : 0;
        sct[t] = v;
        __syncthreads();
        for (int off = 1; off < 256; off <<= 1) {
            int u = (t >= off) ? sct[t - off] : 0;
            __syncthreads();
            sct[t] += u;
            __syncthreads();
        }
        if (base + t < nb) bs[base + t] = carry + sct[t] - v;
        carry += sct[255];
        __syncthreads();                    // protect sct[255] before reuse
    }
}

// ---- place edges into bucket runs (LDS cursors; scan fixup via local scan) -
__global__ __launch_bounds__(256) void k_place(const void* __restrict__ e_raw,
                                               const int* __restrict__ histOff,
                                               const int* __restrict__ bsum,
                                               u32* __restrict__ tmp,
                                               int E, int NB, int NC, int nbH) {
    __shared__ int cur[512];
    __shared__ int bs[1024];
    __shared__ int sct[256];
    int c = blockIdx.x;
    int t = threadIdx.x;
    scan_bsum_local(bsum, nbH, bs, sct, t);
    for (int b = t; b < NB; b += 256) {
        int idx = b * NC + c;
        cur[b] = histOff[idx] + bs[idx >> 8];
    }
    __syncthreads();
    const int* e32 = (const int*)e_raw;
    bool is64 = detect_is64(e32, t & 63);
    int j0 = c * CHUNK, j1 = min(E, j0 + CHUNK);
    for (int j = j0 + t; j < j1; j += 256) {
        int s, d;
        if (is64) {
            s = (int)((const long long*)e_raw)[j];
            d = (int)((const long long*)e_raw)[E + j];
        } else {
            s = e32[j];
            d = e32[E + j];
        }
        int pos = atomicAdd(&cur[d >> 8], 1);
        tmp[pos] = (u32)s | ((u32)(d & 255) << 24);   // s < 2^24
    }
}

// ---- fused deg+sort: per-bucket degree, dinv, exact rowStart, then place
//      records into exact per-node CSR order (all LDS-cursor) ---------------
__global__ __launch_bounds__(256) void k_degsort(const u32* __restrict__ tmp,
                                                 const int* __restrict__ histOff,
                                                 const int* __restrict__ bsum,
                                                 int* __restrict__ degI,
                                                 float* __restrict__ dinv,
                                                 int* __restrict__ rs,
                                                 int* __restrict__ eSrc,
                                                 int n, int NB, int NC, int E,
                                                 int nbH) {
    __shared__ int cnt[256];
    __shared__ int sh[256];
    __shared__ int cur[256];
    __shared__ int bs[1024];
    int b = blockIdx.x;
    int t = threadIdx.x;
    scan_bsum_local(bsum, nbH, bs, sh, t);
    cnt[t] = 0;
    __syncthreads();
    int i0 = b * NC;
    int seg0 = histOff[i0] + bs[i0 >> 8];
    int seg1 = E;
    if (b + 1 < NB) {
        int i1 = (b + 1) * NC;
        seg1 = histOff[i1] + bs[i1 >> 8];
    }
    for (int j = seg0 + t; j < seg1; j += 256) atomicAdd(&cnt[tmp[j] >> 24], 1);
    __syncthreads();
    int v = cnt[t];
    sh[t] = v;
    __syncthreads();
    for (int off = 1; off < 256; off <<= 1) {
        int u = (t >= off) ? sh[t - off] : 0;
        __syncthreads();
        sh[t] += u;
        __syncthreads();
    }
    int myStart = seg0 + sh[t] - v;               // exclusive within bucket
    cur[t] = myStart;
    int node = b * 256 + t;
    if (node < n) {
        degI[node] = v;
        dinv[node] = rsqrtf((float)v + 1.0f);     // +1 self-loop
        rs[node] = myStart;
    }
    __syncthreads();
    for (int j = seg0 + t; j < seg1; j += 256) {
        u32 rec = tmp[j];
        int dl = rec >> 24;
        int s = (int)(rec & 0x00FFFFFFu);
        int pos = atomicAdd(&cur[dl], 1);
        eSrc[pos] = s;
    }
}

// ---- wave-per-node gather, 128 feats: uint4 16-lane-group loads (r19) ------
// Wave = 4 groups x 16 lanes; group q handles every 4th edge with a single
// uint4 (16B) row-segment load; lane m covers feats 8m..8m+7. 4x fewer
// memory requests than the dword version; 16-edge block = 8 shfl + 4 ld +
// 32 fma wave-inst (was 80). Cross-group partials: 2 shfl_xor rounds.
// out = relu(dinv_d*(sum dinv_s*h_s + dinv_d*h_d) + b1), packed bf16x2.
__global__ __launch_bounds__(256) void k_gather128(
    const uint4* __restrict__ Hb4, const int* __restrict__ rs,
    const int* __restrict__ degI, const int* __restrict__ eSrc,
    const float* __restrict__ dinv, const float* __restrict__ b1,
    uint4* __restrict__ outb4, int n) {
    const int wave = threadIdx.x >> 6;
    const int lane = threadIdx.x & 63;
    const int q = lane >> 4;               // edge group 0..3
    const int m = lane & 15;               // 16B column within 256B row
    const int node = blockIdx.x * 4 + wave;
    if (node >= n) return;
    const int start = rs[node];
    const int deg = degI[node];
    float a0 = 0.f, a1 = 0.f, a2 = 0.f, a3 = 0.f;
    float a4 = 0.f, a5 = 0.f, a6 = 0.f, a7 = 0.f;

#define GACC(U, W)                                                    \
    a0 = fmaf(W, bflo(U.x), a0); a1 = fmaf(W, bfhi(U.x), a1);         \
    a2 = fmaf(W, bflo(U.y), a2); a3 = fmaf(W, bfhi(U.y), a3);         \
    a4 = fmaf(W, bflo(U.z), a4); a5 = fmaf(W, bfhi(U.z), a5);         \
    a6 = fmaf(W, bflo(U.w), a6); a7 = fmaf(W, bfhi(U.w), a7);

    for (int base = 0; base < deg; base += 64) {
        int mS = 0;
        float mW = 0.f;
        if (base + lane < deg) { mS = eSrc[start + base + lane]; mW = dinv[mS]; }
        int cnt = min(64, deg - base);
        int t = 0;
        for (; t + 16 <= cnt; t += 16) {   // 16 edges: 4/group, 4 ld in flight
            int s0 = __shfl(mS, t + q),      s1 = __shfl(mS, t + 4 + q);
            int s2 = __shfl(mS, t + 8 + q),  s3 = __shfl(mS, t + 12 + q);
            float w0 = __shfl(mW, t + q),     w1 = __shfl(mW, t + 4 + q);
            float w2 = __shfl(mW, t + 8 + q), w3 = __shfl(mW, t + 12 + q);
            uint4 u0 = Hb4[(size_t)s0 * 16 + m];
            uint4 u1 = Hb4[(size_t)s1 * 16 + m];
            uint4 u2 = Hb4[(size_t)s2 * 16 + m];
            uint4 u3 = Hb4[(size_t)s3 * 16 + m];
            GACC(u0, w0)
            GACC(u1, w1)
            GACC(u2, w2)
            GACC(u3, w3)
        }
        for (; t < cnt; t += 4) {          // 4-edge tail; idx<=63 always,
            int idx = t + q;               // idx>=cnt lanes carry mW=0
            int s = __shfl(mS, idx);
            float w = __shfl(mW, idx);
            uint4 u = Hb4[(size_t)s * 16 + m];
            GACC(u, w)
        }
    }
#undef GACC
    // reduce the 4 edge-group partials (lanes m, m+16, m+32, m+48)
#define GRED(v) v += __shfl_xor(v, 16); v += __shfl_xor(v, 32);
    GRED(a0) GRED(a1) GRED(a2) GRED(a3) GRED(a4) GRED(a5) GRED(a6) GRED(a7)
#undef GRED
    if (q == 0) {
        const float di = dinv[node];
        uint4 us = Hb4[(size_t)node * 16 + m];         // self term (unscaled)
        float4 bva = ((const float4*)b1)[m * 2];       // feats 8m..8m+3
        float4 bvb = ((const float4*)b1)[m * 2 + 1];   // feats 8m+4..8m+7
        float i0 = fmaf(di, bflo(us.x), a0), i1 = fmaf(di, bfhi(us.x), a1);
        float i2 = fmaf(di, bflo(us.y), a2), i3 = fmaf(di, bfhi(us.y), a3);
        float i4 = fmaf(di, bflo(us.z), a4), i5 = fmaf(di, bfhi(us.z), a5);
        float i6 = fmaf(di, bflo(us.w), a6), i7 = fmaf(di, bfhi(us.w), a7);
        float r0 = fmaxf(fmaf(di, i0, bva.x), 0.f);
        float r1 = fmaxf(fmaf(di, i1, bva.y), 0.f);
        float r2 = fmaxf(fmaf(di, i2, bva.z), 0.f);
        float r3 = fmaxf(fmaf(di, i3, bva.w), 0.f);
        float r4 = fmaxf(fmaf(di, i4, bvb.x), 0.f);
        float r5 = fmaxf(fmaf(di, i5, bvb.y), 0.f);
        float r6 = fmaxf(fmaf(di, i6, bvb.z), 0.f);
        float r7 = fmaxf(fmaf(di, i7, bvb.w), 0.f);
        uint4 o;
        o.x = pack2(r0, r1);
        o.y = pack2(r2, r3);
        o.z = pack2(r4, r5);
        o.w = pack2(r6, r7);
        outb4[(size_t)node * 16 + m] = o;
    }
}

// ---- GEMM2 (MFMA bf16): A1b[n,64]u32 @ W2 -> H2 SLICE-MAJOR [2][n][20]u16,
//      row*dinv (4MB/slice fits a per-XCD L2 for the sliced gather40) -------
__global__ __launch_bounds__(256) void k_gemm2(const u32* __restrict__ A1b,
                                               const u16* __restrict__ W2Tb,
                                               const float* __restrict__ dinv,
                                               u16* __restrict__ H2s, int n) {
    __shared__ u32 As[64 * 68];
    __shared__ u32 Bs[48 * 68];
    const int tid = threadIdx.x;
    const int row0 = blockIdx.x * 64;
#pragma unroll
    for (int it = 0; it < 4; it++) {        // stage A1 rows (already bf16)
        int i = tid + it * 256;             // 1024 uint4
        int r = i >> 4;
        int c4 = (i & 15) << 2;
        int gr = row0 + r;
        uint4 v = make_uint4(0u, 0u, 0u, 0u);
        if (gr < n) v = *(const uint4*)(A1b + (size_t)gr * 64 + c4);
        *(uint4*)&As[r * 68 + c4] = v;
    }
#pragma unroll
    for (int it = 0; it < 3; it++) {        // stage W2Tb (768 uint4)
        int i = tid + it * 256;
        int r = i >> 4;
        int c4 = (i & 15) << 2;
        *(uint4*)&Bs[r * 68 + c4] =
            *(const uint4*)((const u32*)W2Tb + (size_t)r * 64 + c4);
    }
    __syncthreads();

    const int lane = tid & 63;
    const int wave = tid >> 6;
    const int mrow = lane & 15;
    const int quad = lane >> 4;

    floatx4 acc[3] = {};
    for (int k0 = 0; k0 < 128; k0 += 32) {
        int koff = (k0 >> 1) + quad * 4;
        short8 a = *(const short8*)&As[(wave * 16 + mrow) * 68 + koff];
#pragma unroll
        for (int j = 0; j < 3; j++) {
            short8 b = *(const short8*)&Bs[(j * 16 + mrow) * 68 + koff];
            acc[j] = __builtin_amdgcn_mfma_f32_16x16x32_bf16(a, b, acc[j], 0, 0, 0);
        }
    }
    int gr0 = row0 + wave * 16 + quad * 4;
    float dv[4];
#pragma unroll
    for (int rg = 0; rg < 4; rg++)
        dv[rg] = (gr0 + rg < n) ? dinv[gr0 + rg] : 0.f;
#pragma unroll
    for (int j = 0; j < 3; j++) {
        int gcol = j * 16 + mrow;
        if (gcol < 40) {
            int sl = (gcol >= 20) ? 1 : 0;
            int c = gcol - sl * 20;
            u16* dstp = H2s + (size_t)sl * ((size_t)n * 20);
#pragma unroll
            for (int rg = 0; rg < 4; rg++) {
                int grow = gr0 + rg;
                if (grow < n)
                    dstp[(size_t)grow * 20 + c] = f2bf(dv[rg] * acc[j][rg]);
            }
        }
    }
}

// ---- XCD-sliced gather40: slice = blockIdx&1, H2 slice = 4MB -> L2 ---------
// Wave = 6 subgroups x 10 lanes (60 active); subgroup owns ONE node, lane
// owns u32 column l of the 40B slice row. Broadcast record loads, 8-deep
// rotation pipeline (weightless: H2 pre-scaled by dinv).
__global__ __launch_bounds__(256) void k_gather40(
    const u32* __restrict__ H2b, const int* __restrict__ rs,
    const int* __restrict__ degI, const int* __restrict__ eSrc,
    const float* __restrict__ dinv, const float* __restrict__ b2,
    float* __restrict__ out, int n) {
    const int lane = threadIdx.x & 63;
    const int wave = threadIdx.x >> 6;
    const int g = lane / 10;               // subgroup 0..5; 6 = idle lanes
    const int l = lane - g * 10;           // u32 column 0..9
    const int slice = blockIdx.x & 1;
    const int chunk = blockIdx.x >> 1;
    if (g >= 6) return;
    const u32* __restrict__ Hs = H2b + (size_t)slice * ((size_t)n * 10);

    const int node = chunk * 24 + wave * 6 + g;
    if (node >= n) return;
    const int start = rs[node];
    const int deg = degI[node];
    float ax = 0.f, ay = 0.f;
    u32 r0, r1, r2, r3, r4, r5, r6, r7;
    u32 u0, u1, u2, u3, u4, u5, u6, u7;
    int t = 0;

#define PH(K) u##K = Hs[(size_t)r##K * 10 + l];
#define PF(K) r##K = (u32)eSrc[bq + K];
#define PA(K) ax += bflo(u##K); ay += bfhi(u##K);

    if (deg >= 8) {
        int bq = start;
        REP8(PF)
        for (; t + 16 <= deg; t += 8) {
            REP8(PH)                        // 8 gathers (records resident)
            bq = start + t + 8;
            REP8(PF)                        // 8 refills stay in flight
            REP8(PA)
        }
        REP8(PH)                            // drain
        REP8(PA)
        t += 8;
    }
    if (t < deg) {                          // masked tail, rem 1..7
        const int bq = start + t;
        const int rm = deg - t - 1;         // 0..6
#define PTF(K) r##K = (u32)eSrc[bq + min(K, rm)];
#define PTA(K) if (K <= rm) { ax += bflo(u##K); ay += bfhi(u##K); }
        REP7(PTF)
        REP7(PH)
        REP7(PTA)
#undef PTF
#undef PTA
    }
#undef PH
#undef PF
#undef PA
    const float di = dinv[node];
    const u32 us = Hs[(size_t)node * 10 + l];          // pre-scaled self term
    const float2 bv = *(const float2*)(b2 + (slice * 10 + l) * 2);
    float ox = fmaf(di, ax + bflo(us), bv.x);
    float oy = fmaf(di, ay + bfhi(us), bv.y);
    *(float2*)(out + (size_t)node * 40 + (slice * 10 + l) * 2) =
        make_float2(ox, oy);
}

extern "C" void kernel_launch(void* const* d_in, const int* in_sizes, int n_in,
                              void* d_out, int out_size, void* d_ws, size_t ws_size,
                              hipStream_t stream) {
    const float* x  = (const float*)d_in[0];
    const void*  e  = d_in[1];
    const float* W1 = (const float*)d_in[2];
    const float* b1 = (const float*)d_in[3];
    const float* W2 = (const float*)d_in[4];
    const float* b2 = (const float*)d_in[5];
    float* out = (float*)d_out;

    const int n = in_sizes[0] / 128;
    const int E = in_sizes[1] / 2;
    const int NB = (n + 255) / 256;          // node buckets (391)
    const int NC = (E + CHUNK - 1) / CHUNK;  // edge chunks (391)
    const int NH = NB * NC;                  // histogram entries (~153k)
    const int nbH = (NH + 255) / 256;        // scan blocks (<=1024)
    const int G1 = (n + 63) / 64;            // gemm1 blocks

    // workspace
    int*   degI    = (int*)d_ws;                     // n
    int*   rs      = degI + n;                       // n
    int*   bsumH   = rs + n;                         // 1024
    float* dinv    = (float*)(bsumH + 1024);         // n
    int*   histG   = (int*)(dinv + n);               // NH
    int*   histOff = histG + NH;                     // NH
    size_t off = (size_t)((char*)(histOff + NH) - (char*)d_ws);
    off = (off + 15) & ~(size_t)15;
    u16*   WTb    = (u16*)((char*)d_ws + off);       // 128*128 bf16 (W1^T)
    u16*   W2Tb   = WTb + 16384;                     // 48*128 bf16 (W2^T pad)
    off = (size_t)((char*)(W2Tb + 6144) - (char*)d_ws);
    off = (off + 15) & ~(size_t)15;
    u32*   tmp    = (u32*)((char*)d_ws + off);       // E bucket records
    int*   eSrc   = (int*)(tmp + (size_t)E);         // E CSR src indices
    u16*   H1s    = (u16*)(eSrc + (size_t)E);        // n*128 bf16 (unscaled)
    uint4* H1q    = (uint4*)H1s;                     // same memory, [n,16]uint4
    u32*   A1b    = (u32*)(H1s + (size_t)n * 128);   // n*64 u32 (relu out)
    uint4* A1q    = (uint4*)A1b;                     // same memory, [n,16]uint4
    u16*   H2s    = (u16*)(A1b + (size_t)n * 64);    // [2][n][20] bf16 (scaled)
    u32*   H2b    = (u32*)H2s;                       // u32 view [2][n][10]

    k_prepW<<<88, 256, 0, stream>>>(W1, W2, WTb, W2Tb);
    k_front<<<NC + G1, 256, 0, stream>>>(e, E, NC, NB, histG, x, WTb, H1s, n);

    k_scan1<<<nbH, 256, 0, stream>>>(histG, histOff, bsumH, NH);
    k_place<<<NC, 256, 0, stream>>>(e, histOff, bsumH, tmp, E, NB, NC, nbH);

    k_degsort<<<NB, 256, 0, stream>>>(tmp, histOff, bsumH, degI, dinv, rs,
                                      eSrc, n, NB, NC, E, nbH);

    k_gather128<<<(n + 3) / 4, 256, 0, stream>>>(H1q, rs, degI, eSrc, dinv,
                                                 b1, A1q, n);
    k_gemm2<<<(n + 63) / 64, 256, 0, stream>>>(A1b, W2Tb, dinv, H2s, n);
    k_gather40<<<2 * ((n + 23) / 24), 256, 0, stream>>>(H2b, rs, degI, eSrc,
                                                        dinv, b2, out, n);
}